// Round 13
// baseline (62.740 us; speedup 1.0000x reference)
//
#include <hip/hip_runtime.h>
#include <hip/hip_bf16.h>

#define E_N 4
#define B_N 64
#define IN_N 4096
#define H_N 4096
#define R_N 512
#define OUT_N 4096
#define TOT_N 8388608  // R*IN + H*R + R*H + OUT*R

typedef float f32x4 __attribute__((ext_vector_type(4)));
typedef short bf16x8 __attribute__((ext_vector_type(8)));
typedef unsigned short u16x8 __attribute__((ext_vector_type(8)));

__device__ __forceinline__ unsigned short f2bf_bits(float f) {
    return __builtin_bit_cast(unsigned short, __float2bfloat16(f));
}
__device__ __forceinline__ float bfbits2f(unsigned short u) {
    return __builtin_bit_cast(float, ((unsigned)u) << 16);
}

__device__ __forceinline__ void stage16(const void* g, void* l) {
    __builtin_amdgcn_global_load_lds(
        (const __attribute__((address_space(1))) void*)g,
        (__attribute__((address_space(3))) void*)l, 16, 0, 0);
}

// Coherent-scope (cross-XCD) store/load: write-through to the coherent point,
// no dirty L2 => no buffer_wbl2 needed for visibility (R8 lesson: __threadfence
// = L2 writeback storm, 500x over-fetch).
__device__ __forceinline__ void store_co4(float* p, float v) {
    asm volatile("global_store_dword %0, %1, off sc0 sc1" :: "v"(p), "v"(v) : "memory");
}
__device__ __forceinline__ f32x4 load_co16(const float* p) {
    f32x4 r;
    asm volatile("global_load_dwordx4 %0, %1, off sc0 sc1" : "=v"(r) : "v"(p) : "memory");
    return r;
}

// C[e,b,n] = sum_k A[e?,b,k] * (W[n,k] + D[e,n,k])
// R12 body (verified 48.5 us).  MODE 0: direct output (opt relu/bf16).
// MODE 1: coherent partial stores + last-block-of-KS-group reduces (ks asc) -> bf16 OutB.
// MODE 2: coherent partial stores + last-block-of-E-group applies scores (e asc) -> f32 finalOut.
// Reduction math bitwise-identical to the old standalone reduce kernels.
template<int K_TOT, int N_TOT, int KS, bool A_SHARED, bool RELU, bool OUT_BF16,
         bool CONV_A, int MODE>
__global__ __launch_bounds__(256, 2)
void gemm_layer(const __hip_bfloat16* __restrict__ A, const float* __restrict__ AF,
                const float* __restrict__ W, const float* __restrict__ D,
                float* __restrict__ OutF, __hip_bfloat16* __restrict__ OutB,
                int* __restrict__ counters, const float* __restrict__ scores,
                float* __restrict__ finalOut)
{
    constexpr int KCH = K_TOT / KS;      // 512 for every layer
    constexpr int NT = N_TOT / 32;
    constexpr int NTILES = KCH / 64;     // 8
    constexpr int BUFSZ = 24576;
    __shared__ __align__(16) char smem[2 * BUFSZ];  // [buf][ Wt 8K | Dt 8K | At 8K ]
    __shared__ int lastFlag;

    const int bid = blockIdx.x;
    const int ks = bid % KS;
    const int nt = (bid / KS) % NT;
    const int e  = bid / (KS * NT);
    const int tid = threadIdx.x;
    const int l  = tid & 63;
    const int w  = tid >> 6;
    const int wn = w & 1;
    const int wm = w >> 1;
    const int lr = l & 15;
    const int lk = (l >> 4) << 3;

    const float* Wb = W + (size_t)(nt * 32) * K_TOT + ks * KCH;
    const float* Db = D + (size_t)e * TOT_N + (size_t)(nt * 32) * K_TOT + ks * KCH;
    const __hip_bfloat16* Ab = A ? (A + (A_SHARED ? (size_t)0 : (size_t)e * B_N * K_TOT)
                                      + ks * KCH) : nullptr;
    const float* AFb = AF ? (AF + (A_SHARED ? (size_t)0 : (size_t)e * B_N * K_TOT)
                                + ks * KCH)
                          : nullptr;

    // 24 1-KB chunks: q 0-7 Wt, 8-15 Dt, 16-23 At.  q = w + 4*i  (i>=4 <=> A chunk)
    const char* gsrc[6];
    int loff[6];
    int lws[6];
    int kstep[6];
    #pragma unroll
    for (int i = 0; i < 6; ++i) {
        const int q = w + i * 4;
        if (q < 8) {
            const int off = q * 1024 + l * 16;
            const int row = off >> 8;
            const int kb  = off & 255;
            gsrc[i] = (const char*)(Wb + (size_t)row * K_TOT) + (kb ^ ((row & 7) << 4));
            loff[i] = q * 1024;
            kstep[i] = 4;
        } else if (q < 16) {
            const int c = q - 8;
            const int off = c * 1024 + l * 16;
            const int row = off >> 8;
            const int kb  = off & 255;
            gsrc[i] = (const char*)(Db + (size_t)row * K_TOT) + (kb ^ ((row & 7) << 4));
            loff[i] = 8192 + c * 1024;
            kstep[i] = 4;
        } else {
            const int c = q - 16;
            const int off = c * 1024 + l * 16;
            const int row = off >> 7;
            const int kb  = off & 127;
            if (CONV_A) {
                gsrc[i] = (const char*)(AFb + (size_t)row * K_TOT) + kb * 2;
                lws[i]  = 16384 + (off & ~127) + (kb ^ ((row & 7) << 4));
                kstep[i] = 4;
            } else {
                gsrc[i] = (const char*)(Ab + (size_t)row * K_TOT) + (kb ^ ((row & 7) << 4));
                loff[i] = 16384 + c * 1024;
                kstep[i] = 2;
            }
        }
    }

    auto stage_all = [&](int kk, char* b) {
        #pragma unroll
        for (int i = 0; i < 6; ++i) {
            if (CONV_A && i >= 4) {
                const char* src = gsrc[i] + (size_t)kk * 4;
                f32x4 a0 = *(const f32x4*)(src);
                f32x4 a1 = *(const f32x4*)(src + 16);
                u16x8 o;
                #pragma unroll
                for (int j = 0; j < 4; ++j) {
                    o[j]     = f2bf_bits(a0[j]);
                    o[j + 4] = f2bf_bits(a1[j]);
                }
                *(u16x8*)(b + lws[i]) = o;
            } else {
                stage16(gsrc[i] + (size_t)kk * kstep[i], b + loff[i]);
            }
        }
    };

    f32x4 acc[2] = {};
    const int wrow = wn * 16 + lr;
    const int wswz = (wrow & 7) << 4;
    const int arow0 = wm * 32 + lr;
    const int aswz = (arow0 & 7) << 4;

    stage_all(0, smem);
    __syncthreads();

    for (int t = 0; t < NTILES; ++t) {
        if (t + 1 < NTILES)
            stage_all((t + 1) * 64, smem + ((t + 1) & 1) * BUFSZ);

        const char* buf = smem + (t & 1) * BUFSZ;
        #pragma unroll
        for (int inner = 0; inner < 2; ++inner) {
            const int b0 = (inner * 32 + lk) * 4;
            const char* wrp = buf + wrow * 256;
            const char* drp = buf + 8192 + wrow * 256;
            f32x4 w0 = *(const f32x4*)(wrp + ((b0)      ^ wswz));
            f32x4 w1 = *(const f32x4*)(wrp + ((b0 + 16) ^ wswz));
            f32x4 d0 = *(const f32x4*)(drp + ((b0)      ^ wswz));
            f32x4 d1 = *(const f32x4*)(drp + ((b0 + 16) ^ wswz));
            f32x4 s0 = w0 + d0;
            f32x4 s1 = w1 + d1;
            bf16x8 bhi, blo;
            #pragma unroll
            for (int j = 0; j < 4; ++j) {
                unsigned short h0 = f2bf_bits(s0[j]);
                bhi[j] = (short)h0;
                blo[j] = (short)f2bf_bits(s0[j] - bfbits2f(h0));
                unsigned short h1 = f2bf_bits(s1[j]);
                bhi[j + 4] = (short)h1;
                blo[j + 4] = (short)f2bf_bits(s1[j] - bfbits2f(h1));
            }
            const int ab = (inner * 32 + lk) * 2;
            #pragma unroll
            for (int mf = 0; mf < 2; ++mf) {
                const int ar = arow0 + mf * 16;
                const char* arp = buf + 16384 + ar * 128;
                bf16x8 af = *(const bf16x8*)(arp + (ab ^ aswz));
                acc[mf] = __builtin_amdgcn_mfma_f32_16x16x32_bf16(af, bhi, acc[mf], 0, 0, 0);
                acc[mf] = __builtin_amdgcn_mfma_f32_16x16x32_bf16(af, blo, acc[mf], 0, 0, 0);
            }
        }
        __syncthreads();
    }

    // C/D layout: col = l&15 (== nrow), row(frag) = (l>>4)*4 + i
    const int rb = (l >> 4) * 4;
    const int nrow = nt * 32 + wrow;
    #pragma unroll
    for (int j = 0; j < 2; ++j) {
        #pragma unroll
        for (int i = 0; i < 4; ++i) {
            const int row = wm * 32 + j * 16 + rb + i;
            float v = acc[j][i];
            if (RELU) v = fmaxf(v, 0.0f);
            if (MODE == 0) {
                if (OUT_BF16)
                    OutB[(size_t)e * B_N * N_TOT + (size_t)row * N_TOT + nrow] =
                        __float2bfloat16(v);
                else
                    OutF[(size_t)(e * KS + ks) * B_N * N_TOT + (size_t)row * N_TOT + nrow] = v;
            } else {
                // coherent write-through partial (visible cross-XCD after vmcnt drain)
                store_co4(OutF + (size_t)(e * KS + ks) * B_N * N_TOT
                               + (size_t)row * N_TOT + nrow, v);
            }
        }
    }

    if (MODE == 0) return;

    // ---- fused tail reduce: last arriving block of the group reduces ----
    asm volatile("s_waitcnt vmcnt(0)" ::: "memory");   // own wave's partials at coherent point
    __syncthreads();                                   // all waves drained
    if (tid == 0) {
        const int g    = (MODE == 1) ? (e * NT + nt) : nt;
        const int need = (MODE == 1) ? KS : E_N;
        lastFlag = (atomicAdd(&counters[g], 1) == need - 1);
    }
    __syncthreads();
    if (!lastFlag) return;

    const int row = tid >> 2;          // 0..63
    const int c0  = (tid & 3) * 8;     // 8 cols each
    const int col = nt * 32 + c0;

    if (MODE == 1) {
        // bf16( sum_ks P[e,ks,b,col..] ), ks ascending — bitwise == old reduce_ks
        const float* base = OutF + (size_t)(e * KS) * B_N * N_TOT
                                 + (size_t)row * N_TOT + col;
        f32x4 v0[KS], v1[KS];
        #pragma unroll
        for (int k = 0; k < KS; ++k) {
            const float* p = base + (size_t)k * B_N * N_TOT;
            v0[k] = load_co16(p);
            v1[k] = load_co16(p + 4);
        }
        asm volatile("s_waitcnt vmcnt(0)" ::: "memory");
        __builtin_amdgcn_sched_barrier(0);
        f32x4 s0 = {}, s1 = {};
        #pragma unroll
        for (int k = 0; k < KS; ++k) { s0 += v0[k]; s1 += v1[k]; }
        u16x8 o;
        #pragma unroll
        for (int j = 0; j < 4; ++j) {
            o[j]     = f2bf_bits(s0[j]);
            o[j + 4] = f2bf_bits(s1[j]);
        }
        *(u16x8*)(OutB + (size_t)e * B_N * N_TOT + (size_t)row * N_TOT + col) = o;
    } else {
        // sum_e scores[e] * P[e,b,col..], e ascending — bitwise == old reduce_experts
        const float* base = OutF + (size_t)row * N_TOT + col;
        f32x4 v0[E_N], v1[E_N];
        #pragma unroll
        for (int e2 = 0; e2 < E_N; ++e2) {
            const float* p = base + (size_t)e2 * B_N * N_TOT;
            v0[e2] = load_co16(p);
            v1[e2] = load_co16(p + 4);
        }
        asm volatile("s_waitcnt vmcnt(0)" ::: "memory");
        __builtin_amdgcn_sched_barrier(0);
        f32x4 a0 = {}, a1 = {};
        #pragma unroll
        for (int e2 = 0; e2 < E_N; ++e2) {
            const float s = scores[e2];
            a0 += s * v0[e2];
            a1 += s * v1[e2];
        }
        float* op = finalOut + (size_t)row * N_TOT + col;
        *(f32x4*)(op)     = a0;
        *(f32x4*)(op + 4) = a1;
    }
}

extern "C" void kernel_launch(void* const* d_in, const int* in_sizes, int n_in,
                              void* d_out, int out_size, void* d_ws, size_t ws_size,
                              hipStream_t stream)
{
    const float* x      = (const float*)d_in[0];
    const float* scores = (const float*)d_in[1];
    const float* delta  = (const float*)d_in[2];
    const float* W1     = (const float*)d_in[3];
    const float* W2     = (const float*)d_in[4];
    const float* W3     = (const float*)d_in[5];
    const float* W4     = (const float*)d_in[6];
    float* out = (float*)d_out;

    char* ws = (char*)d_ws;
    __hip_bfloat16* h1b = (__hip_bfloat16*)(ws + 524288);           // 256 KB
    __hip_bfloat16* h2b = (__hip_bfloat16*)(ws + 786432);           // 2 MB
    __hip_bfloat16* h3b = (__hip_bfloat16*)(ws + 2883584);          // 256 KB
    float* P1 = (float*)(ws + 3145728);                             // 4 MB
    float* P3 = (float*)(ws + 7340032);                             // 4 MB
    float* P4 = (float*)(ws + 11534336);                            // 4 MB
    int* cnt  = (int*)(ws + 15728640);                              // 1 KB (256 ints)

    const float* d1 = delta;
    const float* d2 = d1 + (size_t)R_N * IN_N;
    const float* d3 = d2 + (size_t)H_N * R_N;
    const float* d4 = d3 + (size_t)R_N * H_N;

    // zero group counters (L1: 0-63, L3: 64-127, L4: 128-255) — every launch
    hipMemsetAsync(cnt, 0, 1024, stream);

    // L1: K=4096, N=512, KS=8, CONV_A (x f32 in-kernel), fused ks-reduce -> h1b
    gemm_layer<IN_N, R_N, 8, true, false, false, true, 1>
        <<<dim3(E_N * (R_N / 32) * 8), dim3(256), 0, stream>>>(
            nullptr, x, W1, d1, P1, h1b, cnt, nullptr, nullptr);

    // L2: K=512, N=4096, relu -> bf16 direct
    gemm_layer<R_N, H_N, 1, false, true, true, false, 0>
        <<<dim3(E_N * (H_N / 32)), dim3(256), 0, stream>>>(
            h1b, nullptr, W2, d2, nullptr, h2b, nullptr, nullptr, nullptr);

    // L3: K=4096, N=512, KS=8, fused ks-reduce -> h3b
    gemm_layer<H_N, R_N, 8, false, false, false, false, 1>
        <<<dim3(E_N * (R_N / 32) * 8), dim3(256), 0, stream>>>(
            h2b, nullptr, W3, d3, P3, h3b, cnt + 64, nullptr, nullptr);

    // L4: K=512, N=4096, fused expert combine (scores) -> out f32
    gemm_layer<R_N, OUT_N, 1, false, false, false, false, 2>
        <<<dim3(E_N * (OUT_N / 32)), dim3(256), 0, stream>>>(
            h3b, nullptr, W4, d4, P4, nullptr, cnt + 128, scores, out);
}